// Round 1
// baseline (2215.853 us; speedup 1.0000x reference)
//
#include <hip/hip_runtime.h>
#include <cstdint>
#include <cstddef>

typedef unsigned long long u64;

#define NB 16
#define NC 64
#define NN 4096
#define NM 1024
#define NK 32

// ---------- helpers ----------

__device__ __forceinline__ u64 shflx64(u64 v, int m) {
  int lo = __shfl_xor((int)(unsigned)(v & 0xffffffffull), m, 64);
  int hi = __shfl_xor((int)(unsigned)(v >> 32), m, 64);
  return ((u64)(unsigned)hi << 32) | (unsigned)lo;
}

// monotone-increasing mapping float -> u32 (handles negative d2 from cancellation)
__device__ __forceinline__ u64 packf(float d, unsigned p) {
  unsigned u = __float_as_uint(d);
  u = (u & 0x80000000u) ? ~u : (u | 0x80000000u);
  return ((u64)u << 32) | p;
}

// ---------- kernel 1: feat (b,c,n) -> featT (b,n,c) ----------

__global__ __launch_bounds__(256) void transpose_feat(const float* __restrict__ feat,
                                                      float* __restrict__ featT) {
  int g = blockIdx.x * 256 + threadIdx.x;     // < NB*NN*NC
  int c = g & 63;
  int n = (g >> 6) & 4095;
  int b = g >> 18;
  featT[g] = feat[((size_t)(b * NC + c)) * NN + n];
}

// ---------- kernel 2: farthest point sampling (one block per batch) ----------

__global__ __launch_bounds__(1024) void fps_kernel(const float* __restrict__ loc,
                                                   float* __restrict__ out_setloc,
                                                   float* __restrict__ ws_setloc) {
  __shared__ float lx[NN], ly[NN], lz[NN];
  __shared__ u64 red[2][16];
  const int b = blockIdx.x;
  const int tid = threadIdx.x;
  const int lane = tid & 63, wid = tid >> 6;
  const float* Lx = loc + (size_t)b * 3 * NN;
  const float* Ly = Lx + NN;
  const float* Lz = Ly + NN;
  float px[4], py[4], pz[4], dist[4];
#pragma unroll
  for (int j = 0; j < 4; ++j) {
    int p = tid + 1024 * j;
    float xx = Lx[p], yy = Ly[p], zz = Lz[p];
    lx[p] = xx; ly[p] = yy; lz[p] = zz;
    px[j] = xx; py[j] = yy; pz[j] = zz;
    dist[j] = __int_as_float(0x7f800000);  // +inf
  }
  __syncthreads();
  int cur = 0;
  for (int s = 0; s < NM; ++s) {
    float xc = lx[cur], yc = ly[cur], zc = lz[cur];
    if (tid == 0) {
      out_setloc[(b * 3 + 0) * NM + s] = xc;
      out_setloc[(b * 3 + 1) * NM + s] = yc;
      out_setloc[(b * 3 + 2) * NM + s] = zc;
      ws_setloc[(b * 3 + 0) * NM + s] = xc;
      ws_setloc[(b * 3 + 1) * NM + s] = yc;
      ws_setloc[(b * 3 + 2) * NM + s] = zc;
    }
    float bd = -1.0f;
    int bp = 0;
#pragma unroll
    for (int j = 0; j < 4; ++j) {
      // match numpy: plain mul, left-assoc adds, no contraction
      float dx = __fsub_rn(px[j], xc);
      float dy = __fsub_rn(py[j], yc);
      float dz = __fsub_rn(pz[j], zc);
      float d2 = __fadd_rn(__fadd_rn(__fmul_rn(dx, dx), __fmul_rn(dy, dy)), __fmul_rn(dz, dz));
      float nd = fminf(dist[j], d2);
      dist[j] = nd;
      if (nd > bd) { bd = nd; bp = tid + 1024 * j; }  // strict > keeps lowest p
    }
    // key: max dist, tie -> min index (via 4095-p in low word)
    u64 key = ((u64)__float_as_uint(bd) << 32) | (unsigned)(4095 - bp);
    u64 o;
    o = shflx64(key, 32); key = o > key ? o : key;
    o = shflx64(key, 16); key = o > key ? o : key;
    o = shflx64(key, 8);  key = o > key ? o : key;
    o = shflx64(key, 4);  key = o > key ? o : key;
    o = shflx64(key, 2);  key = o > key ? o : key;
    o = shflx64(key, 1);  key = o > key ? o : key;
    if (lane == 0) red[s & 1][wid] = key;
    __syncthreads();
    u64 k2 = red[s & 1][lane & 15];
    o = shflx64(k2, 8); k2 = o > k2 ? o : k2;
    o = shflx64(k2, 4); k2 = o > k2 ? o : k2;
    o = shflx64(k2, 2); k2 = o > k2 ? o : k2;
    o = shflx64(k2, 1); k2 = o > k2 ? o : k2;
    cur = 4095 - (int)(unsigned)(k2 & 0xffffffffull);
  }
}

// ---------- kernel 3: kNN (one wave per query) ----------

__global__ __launch_bounds__(256) void knn_kernel(const float* __restrict__ loc,
                                                  const float* __restrict__ ws_setloc,
                                                  int* __restrict__ ws_knn) {
  const int wq = blockIdx.x * 4 + (threadIdx.x >> 6);  // query id, < NB*NM
  const int lane = threadIdx.x & 63;
  const int b = wq >> 10, mq = wq & 1023;
  const float* Sb = ws_setloc + (size_t)b * 3 * NM;
  float xs = Sb[mq], ys = Sb[NM + mq], zs = Sb[2 * NM + mq];
  float sqs = __fadd_rn(__fadd_rn(__fmul_rn(xs, xs), __fmul_rn(ys, ys)), __fmul_rn(zs, zs));
  const float* Lx = loc + (size_t)b * 3 * NN;
  const float* Ly = Lx + NN;
  const float* Lz = Ly + NN;
  float Dv[64];
  u64 k1 = ~0ull, k2v = ~0ull;
#pragma unroll
  for (int j = 0; j < 64; ++j) {
    int p = j * 64 + lane;
    float x = Lx[p], y = Ly[p], z = Lz[p];
    float sql = __fadd_rn(__fadd_rn(__fmul_rn(x, x), __fmul_rn(y, y)), __fmul_rn(z, z));
    float cr  = __fadd_rn(__fadd_rn(__fmul_rn(xs, x), __fmul_rn(ys, y)), __fmul_rn(zs, z));
    float d2  = __fsub_rn(__fadd_rn(sqs, sql), __fmul_rn(2.0f, cr));
    Dv[j] = d2;
    u64 kk = packf(d2, (unsigned)p);
    if (kk < k1) { k2v = k1; k1 = kk; }
    else if (kk < k2v) { k2v = kk; }
  }
  u64 usedm = 0;
  int* outp = ws_knn + (size_t)wq * NK;
  for (int s = 0; s < NK; ++s) {
    u64 w = k1, o;
    o = shflx64(w, 32); w = o < w ? o : w;
    o = shflx64(w, 16); w = o < w ? o : w;
    o = shflx64(w, 8);  w = o < w ? o : w;
    o = shflx64(w, 4);  w = o < w ? o : w;
    o = shflx64(w, 2);  w = o < w ? o : w;
    o = shflx64(w, 1);  w = o < w ? o : w;
    if (lane == 0) outp[s] = (int)(unsigned)(w & 0xffffffffull);
    if (k1 == w) {  // unique owner (indices unique)
      unsigned pw = (unsigned)(w & 0xffffffffull);
      usedm |= 1ull << (pw >> 6);
      k1 = k2v; k2v = ~0ull;
      if (k1 == ~0ull) {  // refill from register-cached distances
#pragma unroll
        for (int j = 0; j < 64; ++j) {
          if (!((usedm >> j) & 1ull)) {
            u64 kk = packf(Dv[j], (unsigned)(j * 64 + lane));
            if (kk < k1) { k2v = k1; k1 = kk; }
            else if (kk < k2v) { k2v = kk; }
          }
        }
      }
    }
  }
}

// ---------- kernel 4: fused gather + 3-layer MLP + maxpool ----------

#define RELU8() { a0=fmaxf(a0,0.f); a1=fmaxf(a1,0.f); a2=fmaxf(a2,0.f); a3=fmaxf(a3,0.f); \
                  a4=fmaxf(a4,0.f); a5=fmaxf(a5,0.f); a6=fmaxf(a6,0.f); a7=fmaxf(a7,0.f); }
#define SCROW(Y, base) { Y[base]=a0; Y[base+1]=a1; Y[base+2]=a2; Y[base+3]=a3; \
                         Y[base+4]=a4; Y[base+5]=a5; Y[base+6]=a6; Y[base+7]=a7; }
#define SCAT8(Y) switch (ob) { \
    case 0: SCROW(Y, 0) break;  case 1: SCROW(Y, 8) break; \
    case 2: SCROW(Y, 16) break; case 3: SCROW(Y, 24) break; \
    case 4: SCROW(Y, 32) break; case 5: SCROW(Y, 40) break; \
    case 6: SCROW(Y, 48) break; case 7: SCROW(Y, 56) break; }
#define BFLY(a) { a = fmaxf(a, __shfl_xor(a, 16, 64)); a = fmaxf(a, __shfl_xor(a, 8, 64)); \
                  a = fmaxf(a, __shfl_xor(a, 4, 64));  a = fmaxf(a, __shfl_xor(a, 2, 64)); \
                  a = fmaxf(a, __shfl_xor(a, 1, 64)); }

__global__ __launch_bounds__(256) void mlp_kernel(
    const float* __restrict__ featT, const float* __restrict__ loc,
    const float* __restrict__ ws_setloc, const int* __restrict__ ws_knn,
    const float* __restrict__ W1, const float* __restrict__ b1,
    const float* __restrict__ W2, const float* __restrict__ b2,
    const float* __restrict__ W3, const float* __restrict__ b3,
    float* __restrict__ out) {
  const int lane = threadIdx.x & 63;
  const int wix = blockIdx.x * 4 + (threadIdx.x >> 6);  // wave id, < 8192
  const int q = wix * 2 + (lane >> 5);                  // query id, < 16384
  const int col = lane & 31;                            // neighbor slot (k)
  const int b = q >> 10, mq = q & 1023;
  const int nk = ws_knn[(size_t)q * NK + col];

  // gather input column: 64 feat channels + 3 rel-loc
  const float* fx = featT + ((size_t)(b * NN + nk)) * 64;
  float x[67];
#pragma unroll
  for (int i = 0; i < 16; ++i) {
    float4 v = *(const float4*)(fx + 4 * i);
    x[4 * i] = v.x; x[4 * i + 1] = v.y; x[4 * i + 2] = v.z; x[4 * i + 3] = v.w;
  }
  {
    const float* Lb = loc + (size_t)b * 3 * NN;
    const float* Sb = ws_setloc + (size_t)b * 3 * NM;
    x[64] = Lb[nk] - Sb[mq];
    x[65] = Lb[NN + nk] - Sb[NM + mq];
    x[66] = Lb[2 * NN + nk] - Sb[2 * NM + mq];
  }

  // layer 1: 67 -> 64
  float y1[64];
#pragma unroll 1
  for (int ob = 0; ob < 8; ++ob) {
    const float* wr = W1 + (size_t)ob * 8 * 67;
    const float* bb = b1 + ob * 8;
    float a0 = bb[0], a1 = bb[1], a2 = bb[2], a3 = bb[3];
    float a4 = bb[4], a5 = bb[5], a6 = bb[6], a7 = bb[7];
#pragma unroll
    for (int c = 0; c < 67; ++c) {
      float xc = x[c];
      a0 = fmaf(wr[c], xc, a0);
      a1 = fmaf(wr[67 + c], xc, a1);
      a2 = fmaf(wr[134 + c], xc, a2);
      a3 = fmaf(wr[201 + c], xc, a3);
      a4 = fmaf(wr[268 + c], xc, a4);
      a5 = fmaf(wr[335 + c], xc, a5);
      a6 = fmaf(wr[402 + c], xc, a6);
      a7 = fmaf(wr[469 + c], xc, a7);
    }
    RELU8();
    SCAT8(y1);
  }

  // layer 2: 64 -> 64
  float y2[64];
#pragma unroll 1
  for (int ob = 0; ob < 8; ++ob) {
    const float* wr = W2 + (size_t)ob * 8 * 64;
    const float* bb = b2 + ob * 8;
    float a0 = bb[0], a1 = bb[1], a2 = bb[2], a3 = bb[3];
    float a4 = bb[4], a5 = bb[5], a6 = bb[6], a7 = bb[7];
#pragma unroll
    for (int c = 0; c < 64; ++c) {
      float xc = y1[c];
      a0 = fmaf(wr[c], xc, a0);
      a1 = fmaf(wr[64 + c], xc, a1);
      a2 = fmaf(wr[128 + c], xc, a2);
      a3 = fmaf(wr[192 + c], xc, a3);
      a4 = fmaf(wr[256 + c], xc, a4);
      a5 = fmaf(wr[320 + c], xc, a5);
      a6 = fmaf(wr[384 + c], xc, a6);
      a7 = fmaf(wr[448 + c], xc, a7);
    }
    RELU8();
    SCAT8(y2);
  }

  // layer 3: 64 -> 128, fused maxpool over the 32 columns + store
#pragma unroll 1
  for (int ob = 0; ob < 16; ++ob) {
    const float* wr = W3 + (size_t)ob * 8 * 64;
    const float* bb = b3 + ob * 8;
    float a0 = bb[0], a1 = bb[1], a2 = bb[2], a3 = bb[3];
    float a4 = bb[4], a5 = bb[5], a6 = bb[6], a7 = bb[7];
#pragma unroll
    for (int c = 0; c < 64; ++c) {
      float xc = y2[c];
      a0 = fmaf(wr[c], xc, a0);
      a1 = fmaf(wr[64 + c], xc, a1);
      a2 = fmaf(wr[128 + c], xc, a2);
      a3 = fmaf(wr[192 + c], xc, a3);
      a4 = fmaf(wr[256 + c], xc, a4);
      a5 = fmaf(wr[320 + c], xc, a5);
      a6 = fmaf(wr[384 + c], xc, a6);
      a7 = fmaf(wr[448 + c], xc, a7);
    }
    RELU8();
    BFLY(a0); BFLY(a1); BFLY(a2); BFLY(a3);
    BFLY(a4); BFLY(a5); BFLY(a6); BFLY(a7);
    if (col == 0) {
      float* op = out + ((size_t)b * 128 + ob * 8) * NM + mq;
      op[0] = a0;       op[NM] = a1;     op[2 * NM] = a2; op[3 * NM] = a3;
      op[4 * NM] = a4;  op[5 * NM] = a5; op[6 * NM] = a6; op[7 * NM] = a7;
    }
  }
}

// ---------- launch ----------

extern "C" void kernel_launch(void* const* d_in, const int* in_sizes, int n_in,
                              void* d_out, int out_size, void* d_ws, size_t ws_size,
                              hipStream_t stream) {
  (void)in_sizes; (void)n_in; (void)out_size; (void)ws_size;
  const float* feat = (const float*)d_in[0];
  const float* loc  = (const float*)d_in[1];
  const float* W1   = (const float*)d_in[2];
  const float* b1   = (const float*)d_in[3];
  const float* W2   = (const float*)d_in[4];
  const float* b2   = (const float*)d_in[5];
  const float* W3   = (const float*)d_in[6];
  const float* b3   = (const float*)d_in[7];
  float* out = (float*)d_out;

  char* ws = (char*)d_ws;
  float* ws_setloc = (float*)ws;                                   // 16*3*1024 f32 = 192 KB
  int*   ws_knn    = (int*)(ws + 196608);                          // 16*1024*32 i32 = 2 MB
  float* ws_featT  = (float*)(ws + 196608 + 2097152);              // 16*4096*64 f32 = 16.75 MB

  float* out_setfeat = out;                    // (16,128,1024)
  float* out_setloc  = out + (size_t)NB * 128 * NM;  // (16,3,1024)

  transpose_feat<<<dim3((NB * NN * NC) / 256), dim3(256), 0, stream>>>(feat, ws_featT);
  fps_kernel<<<dim3(NB), dim3(1024), 0, stream>>>(loc, out_setloc, ws_setloc);
  knn_kernel<<<dim3((NB * NM) / 4), dim3(256), 0, stream>>>(loc, ws_setloc, ws_knn);
  mlp_kernel<<<dim3((NB * NM) / 8), dim3(256), 0, stream>>>(
      ws_featT, loc, ws_setloc, ws_knn, W1, b1, W2, b2, W3, b3, out_setfeat);
}

// Round 2
// 2204.635 us; speedup vs baseline: 1.0051x; 1.0051x over previous
//
#include <hip/hip_runtime.h>
#include <cstdint>
#include <cstddef>

typedef unsigned long long u64;

#define NB 16
#define NC 64
#define NN 4096
#define NM 1024
#define NK 32

// ---------- DPP wave-reduction helpers (row_shr 1/2/4/8 + row_bcast 15/31) ----------

template <int C>
__device__ __forceinline__ float dppf(float x, float ident) {
  return __int_as_float(__builtin_amdgcn_update_dpp(
      __float_as_int(ident), __float_as_int(x), C, 0xf, 0xf, false));
}

template <int C>
__device__ __forceinline__ unsigned dppu(unsigned x, unsigned ident) {
  return (unsigned)__builtin_amdgcn_update_dpp(
      (int)ident, (int)x, C, 0xf, 0xf, false);
}

// full-wave (64-lane) float max; result broadcast via readlane(63)
__device__ __forceinline__ float wave_fmax(float x) {
  const float I = __int_as_float(0xff800000);  // -inf
  x = fmaxf(x, dppf<0x111>(x, I));
  x = fmaxf(x, dppf<0x112>(x, I));
  x = fmaxf(x, dppf<0x114>(x, I));
  x = fmaxf(x, dppf<0x118>(x, I));
  x = fmaxf(x, dppf<0x142>(x, I));  // row_bcast:15
  x = fmaxf(x, dppf<0x143>(x, I));  // row_bcast:31
  return __int_as_float(__builtin_amdgcn_readlane(__float_as_int(x), 63));
}

__device__ __forceinline__ float wave_fmin(float x) {
  const float I = __int_as_float(0x7f800000);  // +inf
  x = fminf(x, dppf<0x111>(x, I));
  x = fminf(x, dppf<0x112>(x, I));
  x = fminf(x, dppf<0x114>(x, I));
  x = fminf(x, dppf<0x118>(x, I));
  x = fminf(x, dppf<0x142>(x, I));
  x = fminf(x, dppf<0x143>(x, I));
  return __int_as_float(__builtin_amdgcn_readlane(__float_as_int(x), 63));
}

__device__ __forceinline__ unsigned wave_umin(unsigned x) {
  const unsigned I = 0xFFFFFFFFu;
  unsigned t;
  t = dppu<0x111>(x, I); x = x < t ? x : t;
  t = dppu<0x112>(x, I); x = x < t ? x : t;
  t = dppu<0x114>(x, I); x = x < t ? x : t;
  t = dppu<0x118>(x, I); x = x < t ? x : t;
  t = dppu<0x142>(x, I); x = x < t ? x : t;
  t = dppu<0x143>(x, I); x = x < t ? x : t;
  return (unsigned)__builtin_amdgcn_readlane((int)x, 63);
}

// ---------- kernel 1: feat (b,c,n) -> featT (b,n,c) ----------

__global__ __launch_bounds__(256) void transpose_feat(const float* __restrict__ feat,
                                                      float* __restrict__ featT) {
  int g = blockIdx.x * 256 + threadIdx.x;     // < NB*NN*NC
  int c = g & 63;
  int n = (g >> 6) & 4095;
  int b = g >> 18;
  featT[g] = feat[((size_t)(b * NC + c)) * NN + n];
}

// ---------- kernel 2: farthest point sampling (one block per batch) ----------
// thread t owns CONTIGUOUS points 4t..4t+3 so lane order == index order
// (exact first-max tie-break at every level).

__global__ __launch_bounds__(1024) void fps_kernel(const float* __restrict__ loc,
                                                   float* __restrict__ out_setloc,
                                                   float* __restrict__ ws_setloc) {
  __shared__ __align__(16) float lx[NN];
  __shared__ __align__(16) float ly[NN];
  __shared__ __align__(16) float lz[NN];
  __shared__ u64 red[2][16];
  const int b = blockIdx.x;
  const int tid = threadIdx.x;
  const int lane = tid & 63, wid = tid >> 6;
  const float* Lx = loc + (size_t)b * 3 * NN;
  const float* Ly = Lx + NN;
  const float* Lz = Ly + NN;
  const int p0 = tid * 4;
  float4 vx = *(const float4*)(Lx + p0);
  float4 vy = *(const float4*)(Ly + p0);
  float4 vz = *(const float4*)(Lz + p0);
  *(float4*)(lx + p0) = vx;
  *(float4*)(ly + p0) = vy;
  *(float4*)(lz + p0) = vz;
  float px[4] = {vx.x, vx.y, vx.z, vx.w};
  float py[4] = {vy.x, vy.y, vy.z, vy.w};
  float pz[4] = {vz.x, vz.y, vz.z, vz.w};
  float dist[4];
#pragma unroll
  for (int j = 0; j < 4; ++j) dist[j] = __int_as_float(0x7f800000);
  __syncthreads();
  int cur = 0;
  for (int s = 0; s < NM; ++s) {
    float xc = lx[cur], yc = ly[cur], zc = lz[cur];  // broadcast LDS reads
    if (tid == 0) {
      out_setloc[(b * 3 + 0) * NM + s] = xc;
      out_setloc[(b * 3 + 1) * NM + s] = yc;
      out_setloc[(b * 3 + 2) * NM + s] = zc;
      ws_setloc[(b * 3 + 0) * NM + s] = xc;
      ws_setloc[(b * 3 + 1) * NM + s] = yc;
      ws_setloc[(b * 3 + 2) * NM + s] = zc;
    }
    float bd = -1.0f;
    int bp = p0;
#pragma unroll
    for (int j = 0; j < 4; ++j) {
      // match numpy: plain mul, left-assoc adds, no contraction
      float dx = __fsub_rn(px[j], xc);
      float dy = __fsub_rn(py[j], yc);
      float dz = __fsub_rn(pz[j], zc);
      float d2 = __fadd_rn(__fadd_rn(__fmul_rn(dx, dx), __fmul_rn(dy, dy)), __fmul_rn(dz, dz));
      float nd = fminf(dist[j], d2);
      dist[j] = nd;
      if (nd > bd) { bd = nd; bp = p0 + j; }  // strict > keeps lowest index
    }
    // wave-level argmax: DPP value max, then lowest lane among ties (== lowest index)
    float wmax = wave_fmax(bd);
    u64 mask = __ballot(bd == wmax);
    if (lane == __ffsll(mask) - 1) {
      // dist values are >= +0 (never -0/never inf after step 0), so raw f32 bits
      // are monotone; tie -> larger (4095-bp) == smaller index.
      red[s & 1][wid] = ((u64)__float_as_uint(bd) << 32) | (unsigned)(4095 - bp);
    }
    __syncthreads();
    u64 best = red[s & 1][0];
#pragma unroll
    for (int w = 1; w < 16; ++w) {
      u64 t = red[s & 1][w];
      if (t > best) best = t;
    }
    cur = 4095 - (int)(unsigned)(best & 0xffffffffull);
  }
}

// ---------- kernel 3: kNN (one wave per query, DPP-min extraction) ----------

__global__ __launch_bounds__(256) void knn_kernel(const float* __restrict__ loc,
                                                  const float* __restrict__ ws_setloc,
                                                  int* __restrict__ ws_knn) {
  const int wq = blockIdx.x * 4 + (threadIdx.x >> 6);  // query id, < NB*NM
  const int lane = threadIdx.x & 63;
  const int b = wq >> 10, mq = wq & 1023;
  const float* Sb = ws_setloc + (size_t)b * 3 * NM;
  float xs = Sb[mq], ys = Sb[NM + mq], zs = Sb[2 * NM + mq];
  float sqs = __fadd_rn(__fadd_rn(__fmul_rn(xs, xs), __fmul_rn(ys, ys)), __fmul_rn(zs, zs));
  const float* Lx = loc + (size_t)b * 3 * NN;
  const float* Ly = Lx + NN;
  const float* Lz = Ly + NN;
  const float INF = __int_as_float(0x7f800000);

  // per-lane two smallest (value, index); lane owns points p = j*64+lane
  float k1 = INF, k2 = INF;
  unsigned i1 = 0xFFFFFFFFu, i2 = 0xFFFFFFFFu;
#pragma unroll 8
  for (int j = 0; j < 64; ++j) {
    int p = j * 64 + lane;
    float x = Lx[p], y = Ly[p], z = Lz[p];
    float sql = __fadd_rn(__fadd_rn(__fmul_rn(x, x), __fmul_rn(y, y)), __fmul_rn(z, z));
    float cr  = __fadd_rn(__fadd_rn(__fmul_rn(xs, x), __fmul_rn(ys, y)), __fmul_rn(zs, z));
    float d2  = __fsub_rn(__fadd_rn(sqs, sql), __fmul_rn(2.0f, cr));
    if (d2 < k1)      { k2 = k1; i2 = i1; k1 = d2; i1 = (unsigned)p; }
    else if (d2 < k2) { k2 = d2; i2 = (unsigned)p; }
  }

  u64 used = 0;        // per-lane mask of extracted j-slots
  unsigned keep = 0;   // lane s holds round-s winner
  for (int s = 0; s < NK; ++s) {
    float wmin = wave_fmin(k1);
    u64 mask = __ballot(k1 == wmin);
    int ownerLane;
    if (__popcll(mask) > 1) {
      // exact tie-break: smallest global index among tied lanes
      unsigned cand = (k1 == wmin) ? i1 : 0xFFFFFFFFu;
      unsigned minp = wave_umin(cand);
      u64 m2 = __ballot(k1 == wmin && i1 == minp);
      ownerLane = __ffsll(m2) - 1;
    } else {
      ownerLane = __ffsll(mask) - 1;
    }
    unsigned widx = (unsigned)__builtin_amdgcn_readlane((int)i1, ownerLane);
    if (lane == s) keep = widx;
    if (lane == ownerLane) {
      used |= 1ull << (i1 >> 6);
      k1 = k2; i1 = i2;
      k2 = INF; i2 = 0xFFFFFFFFu;
      if (__float_as_uint(k1) == 0x7f800000u) {
        // rare refill: recompute this lane's remaining distances (L2-hot loc)
#pragma unroll 8
        for (int j = 0; j < 64; ++j) {
          if (!((used >> j) & 1ull)) {
            int p = j * 64 + lane;
            float x = Lx[p], y = Ly[p], z = Lz[p];
            float sql = __fadd_rn(__fadd_rn(__fmul_rn(x, x), __fmul_rn(y, y)), __fmul_rn(z, z));
            float cr  = __fadd_rn(__fadd_rn(__fmul_rn(xs, x), __fmul_rn(ys, y)), __fmul_rn(zs, z));
            float d2  = __fsub_rn(__fadd_rn(sqs, sql), __fmul_rn(2.0f, cr));
            if (d2 < k1)      { k2 = k1; i2 = i1; k1 = d2; i1 = (unsigned)p; }
            else if (d2 < k2) { k2 = d2; i2 = (unsigned)p; }
          }
        }
      }
    }
  }
  if (lane < NK) ws_knn[(size_t)wq * NK + lane] = (int)keep;
}

// ---------- kernel 4: fused gather + 3-layer MLP + maxpool ----------

#define RELU8() { a0=fmaxf(a0,0.f); a1=fmaxf(a1,0.f); a2=fmaxf(a2,0.f); a3=fmaxf(a3,0.f); \
                  a4=fmaxf(a4,0.f); a5=fmaxf(a5,0.f); a6=fmaxf(a6,0.f); a7=fmaxf(a7,0.f); }
#define SCROW(Y, base) { Y[base]=a0; Y[base+1]=a1; Y[base+2]=a2; Y[base+3]=a3; \
                         Y[base+4]=a4; Y[base+5]=a5; Y[base+6]=a6; Y[base+7]=a7; }
#define SCAT8(Y) switch (ob) { \
    case 0: SCROW(Y, 0) break;  case 1: SCROW(Y, 8) break; \
    case 2: SCROW(Y, 16) break; case 3: SCROW(Y, 24) break; \
    case 4: SCROW(Y, 32) break; case 5: SCROW(Y, 40) break; \
    case 6: SCROW(Y, 48) break; case 7: SCROW(Y, 56) break; }
#define BFLY(a) { a = fmaxf(a, __shfl_xor(a, 16, 64)); a = fmaxf(a, __shfl_xor(a, 8, 64)); \
                  a = fmaxf(a, __shfl_xor(a, 4, 64));  a = fmaxf(a, __shfl_xor(a, 2, 64)); \
                  a = fmaxf(a, __shfl_xor(a, 1, 64)); }

__global__ __launch_bounds__(256) void mlp_kernel(
    const float* __restrict__ featT, const float* __restrict__ loc,
    const float* __restrict__ ws_setloc, const int* __restrict__ ws_knn,
    const float* __restrict__ W1, const float* __restrict__ b1,
    const float* __restrict__ W2, const float* __restrict__ b2,
    const float* __restrict__ W3, const float* __restrict__ b3,
    float* __restrict__ out) {
  const int lane = threadIdx.x & 63;
  const int wix = blockIdx.x * 4 + (threadIdx.x >> 6);  // wave id, < 8192
  const int q = wix * 2 + (lane >> 5);                  // query id, < 16384
  const int col = lane & 31;                            // neighbor slot (k)
  const int b = q >> 10, mq = q & 1023;
  const int nk = ws_knn[(size_t)q * NK + col];

  // gather input column: 64 feat channels + 3 rel-loc
  const float* fx = featT + ((size_t)(b * NN + nk)) * 64;
  float x[67];
#pragma unroll
  for (int i = 0; i < 16; ++i) {
    float4 v = *(const float4*)(fx + 4 * i);
    x[4 * i] = v.x; x[4 * i + 1] = v.y; x[4 * i + 2] = v.z; x[4 * i + 3] = v.w;
  }
  {
    const float* Lb = loc + (size_t)b * 3 * NN;
    const float* Sb = ws_setloc + (size_t)b * 3 * NM;
    x[64] = Lb[nk] - Sb[mq];
    x[65] = Lb[NN + nk] - Sb[NM + mq];
    x[66] = Lb[2 * NN + nk] - Sb[2 * NM + mq];
  }

  // layer 1: 67 -> 64
  float y1[64];
#pragma unroll 1
  for (int ob = 0; ob < 8; ++ob) {
    const float* wr = W1 + (size_t)ob * 8 * 67;
    const float* bb = b1 + ob * 8;
    float a0 = bb[0], a1 = bb[1], a2 = bb[2], a3 = bb[3];
    float a4 = bb[4], a5 = bb[5], a6 = bb[6], a7 = bb[7];
#pragma unroll
    for (int c = 0; c < 67; ++c) {
      float xc = x[c];
      a0 = fmaf(wr[c], xc, a0);
      a1 = fmaf(wr[67 + c], xc, a1);
      a2 = fmaf(wr[134 + c], xc, a2);
      a3 = fmaf(wr[201 + c], xc, a3);
      a4 = fmaf(wr[268 + c], xc, a4);
      a5 = fmaf(wr[335 + c], xc, a5);
      a6 = fmaf(wr[402 + c], xc, a6);
      a7 = fmaf(wr[469 + c], xc, a7);
    }
    RELU8();
    SCAT8(y1);
  }

  // layer 2: 64 -> 64
  float y2[64];
#pragma unroll 1
  for (int ob = 0; ob < 8; ++ob) {
    const float* wr = W2 + (size_t)ob * 8 * 64;
    const float* bb = b2 + ob * 8;
    float a0 = bb[0], a1 = bb[1], a2 = bb[2], a3 = bb[3];
    float a4 = bb[4], a5 = bb[5], a6 = bb[6], a7 = bb[7];
#pragma unroll
    for (int c = 0; c < 64; ++c) {
      float xc = y1[c];
      a0 = fmaf(wr[c], xc, a0);
      a1 = fmaf(wr[64 + c], xc, a1);
      a2 = fmaf(wr[128 + c], xc, a2);
      a3 = fmaf(wr[192 + c], xc, a3);
      a4 = fmaf(wr[256 + c], xc, a4);
      a5 = fmaf(wr[320 + c], xc, a5);
      a6 = fmaf(wr[384 + c], xc, a6);
      a7 = fmaf(wr[448 + c], xc, a7);
    }
    RELU8();
    SCAT8(y2);
  }

  // layer 3: 64 -> 128, fused maxpool over the 32 columns + store
#pragma unroll 1
  for (int ob = 0; ob < 16; ++ob) {
    const float* wr = W3 + (size_t)ob * 8 * 64;
    const float* bb = b3 + ob * 8;
    float a0 = bb[0], a1 = bb[1], a2 = bb[2], a3 = bb[3];
    float a4 = bb[4], a5 = bb[5], a6 = bb[6], a7 = bb[7];
#pragma unroll
    for (int c = 0; c < 64; ++c) {
      float xc = y2[c];
      a0 = fmaf(wr[c], xc, a0);
      a1 = fmaf(wr[64 + c], xc, a1);
      a2 = fmaf(wr[128 + c], xc, a2);
      a3 = fmaf(wr[192 + c], xc, a3);
      a4 = fmaf(wr[256 + c], xc, a4);
      a5 = fmaf(wr[320 + c], xc, a5);
      a6 = fmaf(wr[384 + c], xc, a6);
      a7 = fmaf(wr[448 + c], xc, a7);
    }
    RELU8();
    BFLY(a0); BFLY(a1); BFLY(a2); BFLY(a3);
    BFLY(a4); BFLY(a5); BFLY(a6); BFLY(a7);
    if (col == 0) {
      float* op = out + ((size_t)b * 128 + ob * 8) * NM + mq;
      op[0] = a0;       op[NM] = a1;     op[2 * NM] = a2; op[3 * NM] = a3;
      op[4 * NM] = a4;  op[5 * NM] = a5; op[6 * NM] = a6; op[7 * NM] = a7;
    }
  }
}

// ---------- launch ----------

extern "C" void kernel_launch(void* const* d_in, const int* in_sizes, int n_in,
                              void* d_out, int out_size, void* d_ws, size_t ws_size,
                              hipStream_t stream) {
  (void)in_sizes; (void)n_in; (void)out_size; (void)ws_size;
  const float* feat = (const float*)d_in[0];
  const float* loc  = (const float*)d_in[1];
  const float* W1   = (const float*)d_in[2];
  const float* b1   = (const float*)d_in[3];
  const float* W2   = (const float*)d_in[4];
  const float* b2   = (const float*)d_in[5];
  const float* W3   = (const float*)d_in[6];
  const float* b3   = (const float*)d_in[7];
  float* out = (float*)d_out;

  char* ws = (char*)d_ws;
  float* ws_setloc = (float*)ws;                                   // 16*3*1024 f32
  int*   ws_knn    = (int*)(ws + 196608);                          // 16*1024*32 i32
  float* ws_featT  = (float*)(ws + 196608 + 2097152);              // 16*4096*64 f32

  float* out_setfeat = out;                          // (16,128,1024)
  float* out_setloc  = out + (size_t)NB * 128 * NM;  // (16,3,1024)

  transpose_feat<<<dim3((NB * NN * NC) / 256), dim3(256), 0, stream>>>(feat, ws_featT);
  fps_kernel<<<dim3(NB), dim3(1024), 0, stream>>>(loc, out_setloc, ws_setloc);
  knn_kernel<<<dim3((NB * NM) / 4), dim3(256), 0, stream>>>(loc, ws_setloc, ws_knn);
  mlp_kernel<<<dim3((NB * NM) / 8), dim3(256), 0, stream>>>(
      ws_featT, loc, ws_setloc, ws_knn, W1, b1, W2, b2, W3, b3, out_setfeat);
}

// Round 3
// 1780.449 us; speedup vs baseline: 1.2445x; 1.2382x over previous
//
#include <hip/hip_runtime.h>
#include <cstdint>
#include <cstddef>

typedef unsigned long long u64;

#define NB 16
#define NC 64
#define NN 4096
#define NM 1024
#define NK 32

// ---------- DPP wave-reduction helpers (row_shr 1/2/4/8 + row_bcast 15/31) ----------

template <int C>
__device__ __forceinline__ float dppf(float x, float ident) {
  return __int_as_float(__builtin_amdgcn_update_dpp(
      __float_as_int(ident), __float_as_int(x), C, 0xf, 0xf, false));
}

template <int C>
__device__ __forceinline__ unsigned dppu(unsigned x, unsigned ident) {
  return (unsigned)__builtin_amdgcn_update_dpp(
      (int)ident, (int)x, C, 0xf, 0xf, false);
}

// full-wave (64-lane) float max; result broadcast via readlane(63)
__device__ __forceinline__ float wave_fmax(float x) {
  const float I = __int_as_float(0xff800000);  // -inf
  x = fmaxf(x, dppf<0x111>(x, I));
  x = fmaxf(x, dppf<0x112>(x, I));
  x = fmaxf(x, dppf<0x114>(x, I));
  x = fmaxf(x, dppf<0x118>(x, I));
  x = fmaxf(x, dppf<0x142>(x, I));  // row_bcast:15
  x = fmaxf(x, dppf<0x143>(x, I));  // row_bcast:31
  return __int_as_float(__builtin_amdgcn_readlane(__float_as_int(x), 63));
}

__device__ __forceinline__ float wave_fmin(float x) {
  const float I = __int_as_float(0x7f800000);  // +inf
  x = fminf(x, dppf<0x111>(x, I));
  x = fminf(x, dppf<0x112>(x, I));
  x = fminf(x, dppf<0x114>(x, I));
  x = fminf(x, dppf<0x118>(x, I));
  x = fminf(x, dppf<0x142>(x, I));
  x = fminf(x, dppf<0x143>(x, I));
  return __int_as_float(__builtin_amdgcn_readlane(__float_as_int(x), 63));
}

__device__ __forceinline__ unsigned wave_umin(unsigned x) {
  const unsigned I = 0xFFFFFFFFu;
  unsigned t;
  t = dppu<0x111>(x, I); x = x < t ? x : t;
  t = dppu<0x112>(x, I); x = x < t ? x : t;
  t = dppu<0x114>(x, I); x = x < t ? x : t;
  t = dppu<0x118>(x, I); x = x < t ? x : t;
  t = dppu<0x142>(x, I); x = x < t ? x : t;
  t = dppu<0x143>(x, I); x = x < t ? x : t;
  return (unsigned)__builtin_amdgcn_readlane((int)x, 63);
}

// ---------- kernel 0: pad W1 (64x67) -> W1p (64x68, zero col 67) ----------

__global__ __launch_bounds__(256) void pad_w1(const float* __restrict__ W1,
                                              float* __restrict__ W1p) {
  int g = blockIdx.x * 256 + threadIdx.x;
  if (g >= 64 * 68) return;
  int o = g / 68, c = g - o * 68;
  W1p[g] = (c < 67) ? W1[o * 67 + c] : 0.0f;
}

// ---------- kernel 1: feat (b,c,n) -> featT (b,n,c) ----------

__global__ __launch_bounds__(256) void transpose_feat(const float* __restrict__ feat,
                                                      float* __restrict__ featT) {
  int g = blockIdx.x * 256 + threadIdx.x;     // < NB*NN*NC
  int c = g & 63;
  int n = (g >> 6) & 4095;
  int b = g >> 18;
  featT[g] = feat[((size_t)(b * NC + c)) * NN + n];
}

// ---------- kernel 2: farthest point sampling ----------
// 256 threads (4 waves, 1/SIMD), 16 CONTIGUOUS points per thread, all coords
// in registers. Winner's coords travel through the reduction (no point LDS).
// One barrier per step, double-buffered float4 candidate slots.

__global__ __launch_bounds__(256) void fps_kernel(const float* __restrict__ loc,
                                                  float* __restrict__ out_setloc,
                                                  float* __restrict__ ws_setloc) {
  __shared__ float4 red[2][4];
  const int b = blockIdx.x;
  const int tid = threadIdx.x;
  const int lane = tid & 63, wid = tid >> 6;
  const float* Lx = loc + (size_t)b * 3 * NN;
  const float* Ly = Lx + NN;
  const float* Lz = Ly + NN;
  const int p0 = tid * 16;
  float px[16], py[16], pz[16], dist[16];
#pragma unroll
  for (int j4 = 0; j4 < 4; ++j4) {
    float4 vx = *(const float4*)(Lx + p0 + 4 * j4);
    float4 vy = *(const float4*)(Ly + p0 + 4 * j4);
    float4 vz = *(const float4*)(Lz + p0 + 4 * j4);
    px[4 * j4] = vx.x; px[4 * j4 + 1] = vx.y; px[4 * j4 + 2] = vx.z; px[4 * j4 + 3] = vx.w;
    py[4 * j4] = vy.x; py[4 * j4 + 1] = vy.y; py[4 * j4 + 2] = vy.z; py[4 * j4 + 3] = vy.w;
    pz[4 * j4] = vz.x; pz[4 * j4 + 1] = vz.y; pz[4 * j4 + 2] = vz.z; pz[4 * j4 + 3] = vz.w;
  }
#pragma unroll
  for (int j = 0; j < 16; ++j) dist[j] = __int_as_float(0x7f800000);
  if (tid == 0) red[1][0] = make_float4(0.0f, px[0], py[0], pz[0]);  // bootstrap: point 0
  __syncthreads();
  float4 boot = red[1][0];
  float sx = boot.y, sy = boot.z, sz = boot.w;

  for (int s = 0; s < NM; ++s) {
    // write current selection (rotating writer wave to spread store issue)
    if (tid == ((s & 3) << 6)) {
      out_setloc[(b * 3 + 0) * NM + s] = sx;
      out_setloc[(b * 3 + 1) * NM + s] = sy;
      out_setloc[(b * 3 + 2) * NM + s] = sz;
      ws_setloc[(b * 3 + 0) * NM + s] = sx;
      ws_setloc[(b * 3 + 1) * NM + s] = sy;
      ws_setloc[(b * 3 + 2) * NM + s] = sz;
    }
    float bd = -1.0f, bx = 0.0f, by = 0.0f, bz = 0.0f;
#pragma unroll
    for (int j = 0; j < 16; ++j) {
      // match numpy: plain mul, left-assoc adds, no contraction
      float dx = __fsub_rn(px[j], sx);
      float dy = __fsub_rn(py[j], sy);
      float dz = __fsub_rn(pz[j], sz);
      float d2 = __fadd_rn(__fadd_rn(__fmul_rn(dx, dx), __fmul_rn(dy, dy)), __fmul_rn(dz, dz));
      float nd = fminf(dist[j], d2);
      dist[j] = nd;
      bool g = nd > bd;  // strict > keeps lowest j (= lowest index)
      bd = g ? nd : bd;
      bx = g ? px[j] : bx;
      by = g ? py[j] : by;
      bz = g ? pz[j] : bz;
    }
    // wave argmax: DPP value max, lowest tied lane (= lowest index) writes cand
    float wmax = wave_fmax(bd);
    u64 m = __ballot(bd == wmax);
    if (lane == __ffsll((long long)m) - 1) red[s & 1][wid] = make_float4(bd, bx, by, bz);
    __syncthreads();
    // 4-way serial argmax, ascending wid + strict > == global first-max
    float4 c0 = red[s & 1][0], c1 = red[s & 1][1], c2 = red[s & 1][2], c3 = red[s & 1][3];
    float bdd = c0.x; sx = c0.y; sy = c0.z; sz = c0.w;
    bool g1 = c1.x > bdd; bdd = g1 ? c1.x : bdd; sx = g1 ? c1.y : sx; sy = g1 ? c1.z : sy; sz = g1 ? c1.w : sz;
    bool g2 = c2.x > bdd; bdd = g2 ? c2.x : bdd; sx = g2 ? c2.y : sx; sy = g2 ? c2.z : sy; sz = g2 ? c2.w : sz;
    bool g3 = c3.x > bdd; bdd = g3 ? c3.x : bdd; sx = g3 ? c3.y : sx; sy = g3 ? c3.z : sy; sz = g3 ? c3.w : sz;
  }
}

// ---------- kernel 3: kNN (one wave per query, DPP-min extraction) ----------

__global__ __launch_bounds__(256) void knn_kernel(const float* __restrict__ loc,
                                                  const float* __restrict__ ws_setloc,
                                                  int* __restrict__ ws_knn) {
  const int wq = blockIdx.x * 4 + (threadIdx.x >> 6);  // query id, < NB*NM
  const int lane = threadIdx.x & 63;
  const int b = wq >> 10, mq = wq & 1023;
  const float* Sb = ws_setloc + (size_t)b * 3 * NM;
  float xs = Sb[mq], ys = Sb[NM + mq], zs = Sb[2 * NM + mq];
  float sqs = __fadd_rn(__fadd_rn(__fmul_rn(xs, xs), __fmul_rn(ys, ys)), __fmul_rn(zs, zs));
  const float* Lx = loc + (size_t)b * 3 * NN;
  const float* Ly = Lx + NN;
  const float* Lz = Ly + NN;
  const float INF = __int_as_float(0x7f800000);

  // per-lane two smallest (value, index); lane owns points p = j*64+lane
  float k1 = INF, k2 = INF;
  unsigned i1 = 0xFFFFFFFFu, i2 = 0xFFFFFFFFu;
#pragma unroll 8
  for (int j = 0; j < 64; ++j) {
    int p = j * 64 + lane;
    float x = Lx[p], y = Ly[p], z = Lz[p];
    float sql = __fadd_rn(__fadd_rn(__fmul_rn(x, x), __fmul_rn(y, y)), __fmul_rn(z, z));
    float cr  = __fadd_rn(__fadd_rn(__fmul_rn(xs, x), __fmul_rn(ys, y)), __fmul_rn(zs, z));
    float d2  = __fsub_rn(__fadd_rn(sqs, sql), __fmul_rn(2.0f, cr));
    if (d2 < k1)      { k2 = k1; i2 = i1; k1 = d2; i1 = (unsigned)p; }
    else if (d2 < k2) { k2 = d2; i2 = (unsigned)p; }
  }

  u64 used = 0;        // per-lane mask of extracted j-slots
  unsigned keep = 0;   // lane s holds round-s winner
  for (int s = 0; s < NK; ++s) {
    float wmin = wave_fmin(k1);
    u64 mask = __ballot(k1 == wmin);
    int ownerLane;
    if (__popcll(mask) > 1) {
      // exact tie-break: smallest global index among tied lanes
      unsigned cand = (k1 == wmin) ? i1 : 0xFFFFFFFFu;
      unsigned minp = wave_umin(cand);
      u64 m2 = __ballot(k1 == wmin && i1 == minp);
      ownerLane = __ffsll((long long)m2) - 1;
    } else {
      ownerLane = __ffsll((long long)mask) - 1;
    }
    unsigned widx = (unsigned)__builtin_amdgcn_readlane((int)i1, ownerLane);
    if (lane == s) keep = widx;
    if (lane == ownerLane) {
      used |= 1ull << (i1 >> 6);
      k1 = k2; i1 = i2;
      k2 = INF; i2 = 0xFFFFFFFFu;
      if (__float_as_uint(k1) == 0x7f800000u) {
        // rare refill: recompute this lane's remaining distances (L2-hot loc)
#pragma unroll 8
        for (int j = 0; j < 64; ++j) {
          if (!((used >> j) & 1ull)) {
            int p = j * 64 + lane;
            float x = Lx[p], y = Ly[p], z = Lz[p];
            float sql = __fadd_rn(__fadd_rn(__fmul_rn(x, x), __fmul_rn(y, y)), __fmul_rn(z, z));
            float cr  = __fadd_rn(__fadd_rn(__fmul_rn(xs, x), __fmul_rn(ys, y)), __fmul_rn(zs, z));
            float d2  = __fsub_rn(__fadd_rn(sqs, sql), __fmul_rn(2.0f, cr));
            if (d2 < k1)      { k2 = k1; i2 = i1; k1 = d2; i1 = (unsigned)p; }
            else if (d2 < k2) { k2 = d2; i2 = (unsigned)p; }
          }
        }
      }
    }
  }
  if (lane < NK) ws_knn[(size_t)wq * NK + lane] = (int)keep;
}

// ---------- kernel 4: fused gather + 3-layer MLP + maxpool ----------

#define RELU8() { a0=fmaxf(a0,0.f); a1=fmaxf(a1,0.f); a2=fmaxf(a2,0.f); a3=fmaxf(a3,0.f); \
                  a4=fmaxf(a4,0.f); a5=fmaxf(a5,0.f); a6=fmaxf(a6,0.f); a7=fmaxf(a7,0.f); }
#define SCROW(Y, base) { Y[base]=a0; Y[base+1]=a1; Y[base+2]=a2; Y[base+3]=a3; \
                         Y[base+4]=a4; Y[base+5]=a5; Y[base+6]=a6; Y[base+7]=a7; }
#define SCAT8(Y) switch (ob) { \
    case 0: SCROW(Y, 0) break;  case 1: SCROW(Y, 8) break; \
    case 2: SCROW(Y, 16) break; case 3: SCROW(Y, 24) break; \
    case 4: SCROW(Y, 32) break; case 5: SCROW(Y, 40) break; \
    case 6: SCROW(Y, 48) break; case 7: SCROW(Y, 56) break; }
#define BFLY(a) { a = fmaxf(a, __shfl_xor(a, 16, 64)); a = fmaxf(a, __shfl_xor(a, 8, 64)); \
                  a = fmaxf(a, __shfl_xor(a, 4, 64));  a = fmaxf(a, __shfl_xor(a, 2, 64)); \
                  a = fmaxf(a, __shfl_xor(a, 1, 64)); }

// one 4-c chunk of row R accumulated into ACC (explicit float4 weight load)
#define ROW4(ACC, R, STRIDE) { \
    float4 w = *(const float4*)(wr + (R) * (STRIDE) + 4 * ch); \
    ACC = fmaf(w.x, x0, ACC); ACC = fmaf(w.y, x1, ACC); \
    ACC = fmaf(w.z, x2, ACC); ACC = fmaf(w.w, x3, ACC); }

#define CHUNK8(XS, STRIDE) { \
    float x0 = XS[4 * ch], x1 = XS[4 * ch + 1], x2 = XS[4 * ch + 2], x3 = XS[4 * ch + 3]; \
    ROW4(a0, 0, STRIDE) ROW4(a1, 1, STRIDE) ROW4(a2, 2, STRIDE) ROW4(a3, 3, STRIDE) \
    ROW4(a4, 4, STRIDE) ROW4(a5, 5, STRIDE) ROW4(a6, 6, STRIDE) ROW4(a7, 7, STRIDE) }

__global__ __launch_bounds__(256) void mlp_kernel(
    const float* __restrict__ featT, const float* __restrict__ loc,
    const float* __restrict__ ws_setloc, const int* __restrict__ ws_knn,
    const float* __restrict__ W1p, const float* __restrict__ b1,
    const float* __restrict__ W2, const float* __restrict__ b2,
    const float* __restrict__ W3, const float* __restrict__ b3,
    float* __restrict__ out) {
  const int lane = threadIdx.x & 63;
  const int wix = blockIdx.x * 4 + (threadIdx.x >> 6);  // wave id, < 8192
  const int q = wix * 2 + (lane >> 5);                  // query id, < 16384
  const int col = lane & 31;                            // neighbor slot (k)
  const int b = q >> 10, mq = q & 1023;
  const int nk = ws_knn[(size_t)q * NK + col];

  // gather input column: 64 feat channels + 3 rel-loc + zero pad
  const float* fx = featT + ((size_t)(b * NN + nk)) * 64;
  float x[68];
#pragma unroll
  for (int i = 0; i < 16; ++i) {
    float4 v = *(const float4*)(fx + 4 * i);
    x[4 * i] = v.x; x[4 * i + 1] = v.y; x[4 * i + 2] = v.z; x[4 * i + 3] = v.w;
  }
  {
    const float* Lb = loc + (size_t)b * 3 * NN;
    const float* Sb = ws_setloc + (size_t)b * 3 * NM;
    x[64] = Lb[nk] - Sb[mq];
    x[65] = Lb[NN + nk] - Sb[NM + mq];
    x[66] = Lb[2 * NN + nk] - Sb[2 * NM + mq];
    x[67] = 0.0f;  // pairs with W1p zero column
  }

  // layer 1: 68 -> 64 (padded)
  float y1[64];
#pragma unroll 1
  for (int ob = 0; ob < 8; ++ob) {
    const float* wr = W1p + (size_t)ob * 8 * 68;
    const float* bb = b1 + ob * 8;
    float a0 = bb[0], a1 = bb[1], a2 = bb[2], a3 = bb[3];
    float a4 = bb[4], a5 = bb[5], a6 = bb[6], a7 = bb[7];
#pragma unroll
    for (int ch = 0; ch < 17; ++ch) CHUNK8(x, 68)
    RELU8();
    SCAT8(y1);
  }

  // layer 2: 64 -> 64
  float y2[64];
#pragma unroll 1
  for (int ob = 0; ob < 8; ++ob) {
    const float* wr = W2 + (size_t)ob * 8 * 64;
    const float* bb = b2 + ob * 8;
    float a0 = bb[0], a1 = bb[1], a2 = bb[2], a3 = bb[3];
    float a4 = bb[4], a5 = bb[5], a6 = bb[6], a7 = bb[7];
#pragma unroll
    for (int ch = 0; ch < 16; ++ch) CHUNK8(y1, 64)
    RELU8();
    SCAT8(y2);
  }

  // layer 3: 64 -> 128, fused maxpool over the 32 columns + store
#pragma unroll 1
  for (int ob = 0; ob < 16; ++ob) {
    const float* wr = W3 + (size_t)ob * 8 * 64;
    const float* bb = b3 + ob * 8;
    float a0 = bb[0], a1 = bb[1], a2 = bb[2], a3 = bb[3];
    float a4 = bb[4], a5 = bb[5], a6 = bb[6], a7 = bb[7];
#pragma unroll
    for (int ch = 0; ch < 16; ++ch) CHUNK8(y2, 64)
    RELU8();
    BFLY(a0); BFLY(a1); BFLY(a2); BFLY(a3);
    BFLY(a4); BFLY(a5); BFLY(a6); BFLY(a7);
    if (col == 0) {
      float* op = out + ((size_t)b * 128 + ob * 8) * NM + mq;
      op[0] = a0;       op[NM] = a1;     op[2 * NM] = a2; op[3 * NM] = a3;
      op[4 * NM] = a4;  op[5 * NM] = a5; op[6 * NM] = a6; op[7 * NM] = a7;
    }
  }
}

// ---------- launch ----------

extern "C" void kernel_launch(void* const* d_in, const int* in_sizes, int n_in,
                              void* d_out, int out_size, void* d_ws, size_t ws_size,
                              hipStream_t stream) {
  (void)in_sizes; (void)n_in; (void)out_size; (void)ws_size;
  const float* feat = (const float*)d_in[0];
  const float* loc  = (const float*)d_in[1];
  const float* W1   = (const float*)d_in[2];
  const float* b1   = (const float*)d_in[3];
  const float* W2   = (const float*)d_in[4];
  const float* b2   = (const float*)d_in[5];
  const float* W3   = (const float*)d_in[6];
  const float* b3   = (const float*)d_in[7];
  float* out = (float*)d_out;

  char* ws = (char*)d_ws;
  float* ws_setloc = (float*)ws;                                   // 16*3*1024 f32
  int*   ws_knn    = (int*)(ws + 196608);                          // 16*1024*32 i32
  float* ws_featT  = (float*)(ws + 196608 + 2097152);              // 16*4096*64 f32
  float* ws_w1p    = (float*)(ws + 196608 + 2097152 + 16777216);   // 64*68 f32

  float* out_setfeat = out;                          // (16,128,1024)
  float* out_setloc  = out + (size_t)NB * 128 * NM;  // (16,3,1024)

  pad_w1<<<dim3(17), dim3(256), 0, stream>>>(W1, ws_w1p);
  transpose_feat<<<dim3((NB * NN * NC) / 256), dim3(256), 0, stream>>>(feat, ws_featT);
  fps_kernel<<<dim3(NB), dim3(256), 0, stream>>>(loc, out_setloc, ws_setloc);
  knn_kernel<<<dim3((NB * NM) / 4), dim3(256), 0, stream>>>(loc, ws_setloc, ws_knn);
  mlp_kernel<<<dim3((NB * NM) / 8), dim3(256), 0, stream>>>(
      ws_featT, loc, ws_setloc, ws_knn, ws_w1p, b1, W2, b2, W3, b3, out_setfeat);
}

// Round 4
// 1713.698 us; speedup vs baseline: 1.2930x; 1.0390x over previous
//
#include <hip/hip_runtime.h>
#include <cstdint>
#include <cstddef>

typedef unsigned long long u64;

#define NB 16
#define NC 64
#define NN 4096
#define NM 1024
#define NK 32

// ---------- DPP wave-reduction helpers (row_shr 1/2/4/8 + row_bcast 15/31) ----------

template <int C>
__device__ __forceinline__ float dppf(float x, float ident) {
  return __int_as_float(__builtin_amdgcn_update_dpp(
      __float_as_int(ident), __float_as_int(x), C, 0xf, 0xf, false));
}

template <int C>
__device__ __forceinline__ unsigned dppu(unsigned x, unsigned ident) {
  return (unsigned)__builtin_amdgcn_update_dpp(
      (int)ident, (int)x, C, 0xf, 0xf, false);
}

// full-wave (64-lane) float max; result broadcast via readlane(63)
__device__ __forceinline__ float wave_fmax(float x) {
  const float I = __int_as_float(0xff800000);  // -inf
  x = fmaxf(x, dppf<0x111>(x, I));
  x = fmaxf(x, dppf<0x112>(x, I));
  x = fmaxf(x, dppf<0x114>(x, I));
  x = fmaxf(x, dppf<0x118>(x, I));
  x = fmaxf(x, dppf<0x142>(x, I));  // row_bcast:15
  x = fmaxf(x, dppf<0x143>(x, I));  // row_bcast:31
  return __int_as_float(__builtin_amdgcn_readlane(__float_as_int(x), 63));
}

__device__ __forceinline__ float wave_fmin(float x) {
  const float I = __int_as_float(0x7f800000);  // +inf
  x = fminf(x, dppf<0x111>(x, I));
  x = fminf(x, dppf<0x112>(x, I));
  x = fminf(x, dppf<0x114>(x, I));
  x = fminf(x, dppf<0x118>(x, I));
  x = fminf(x, dppf<0x142>(x, I));
  x = fminf(x, dppf<0x143>(x, I));
  return __int_as_float(__builtin_amdgcn_readlane(__float_as_int(x), 63));
}

__device__ __forceinline__ unsigned wave_umin(unsigned x) {
  const unsigned I = 0xFFFFFFFFu;
  unsigned t;
  t = dppu<0x111>(x, I); x = x < t ? x : t;
  t = dppu<0x112>(x, I); x = x < t ? x : t;
  t = dppu<0x114>(x, I); x = x < t ? x : t;
  t = dppu<0x118>(x, I); x = x < t ? x : t;
  t = dppu<0x142>(x, I); x = x < t ? x : t;
  t = dppu<0x143>(x, I); x = x < t ? x : t;
  return (unsigned)__builtin_amdgcn_readlane((int)x, 63);
}

// ---------- kernel 0: pad W1 (64x67) -> W1p (64x68, zero col 67) ----------

__global__ __launch_bounds__(256) void pad_w1(const float* __restrict__ W1,
                                              float* __restrict__ W1p) {
  int g = blockIdx.x * 256 + threadIdx.x;
  if (g >= 64 * 68) return;
  int o = g / 68, c = g - o * 68;
  W1p[g] = (c < 67) ? W1[o * 67 + c] : 0.0f;
}

// ---------- kernel 1: feat (b,c,n) -> featT (b,n,c) ----------

__global__ __launch_bounds__(256) void transpose_feat(const float* __restrict__ feat,
                                                      float* __restrict__ featT) {
  int g = blockIdx.x * 256 + threadIdx.x;     // < NB*NN*NC
  int c = g & 63;
  int n = (g >> 6) & 4095;
  int b = g >> 18;
  featT[g] = feat[((size_t)(b * NC + c)) * NN + n];
}

// ---------- kernel 2: farthest point sampling ----------
// 256 threads (4 waves, 1/SIMD), 16 CONTIGUOUS points per thread, coords in
// registers; winner coords travel through the reduction. NO global stores in
// the loop (winners captured in a 4-deep register shift queue per thread,
// one coalesced write at the end) -> barrier never waits on vmcnt drain.

__global__ __launch_bounds__(256) void fps_kernel(const float* __restrict__ loc,
                                                  float* __restrict__ out_setloc) {
  __shared__ float4 red[2][4];
  const int b = blockIdx.x;
  const int tid = threadIdx.x;
  const int lane = tid & 63, wid = tid >> 6;
  const float* Lx = loc + (size_t)b * 3 * NN;
  const float* Ly = Lx + NN;
  const float* Lz = Ly + NN;
  const int p0 = tid * 16;
  float px[16], py[16], pz[16], dist[16];
#pragma unroll
  for (int j4 = 0; j4 < 4; ++j4) {
    float4 vx = *(const float4*)(Lx + p0 + 4 * j4);
    float4 vy = *(const float4*)(Ly + p0 + 4 * j4);
    float4 vz = *(const float4*)(Lz + p0 + 4 * j4);
    px[4 * j4] = vx.x; px[4 * j4 + 1] = vx.y; px[4 * j4 + 2] = vx.z; px[4 * j4 + 3] = vx.w;
    py[4 * j4] = vy.x; py[4 * j4 + 1] = vy.y; py[4 * j4 + 2] = vy.z; py[4 * j4 + 3] = vy.w;
    pz[4 * j4] = vz.x; pz[4 * j4 + 1] = vz.y; pz[4 * j4 + 2] = vz.z; pz[4 * j4 + 3] = vz.w;
  }
#pragma unroll
  for (int j = 0; j < 16; ++j) dist[j] = __int_as_float(0x7f800000);
  if (tid == 0) red[1][0] = make_float4(0.0f, px[0], py[0], pz[0]);  // bootstrap: point 0
  __syncthreads();
  float4 boot = red[1][0];
  float sx = boot.y, sy = boot.z, sz = boot.w;

  // register shift-queue of captured winners (slot s captured by tid == s%256)
  float w0x = 0, w0y = 0, w0z = 0, w1x = 0, w1y = 0, w1z = 0;
  float w2x = 0, w2y = 0, w2z = 0, w3x = 0, w3y = 0, w3z = 0;
  if (tid == 0) { w0x = sx; w0y = sy; w0z = sz; }  // slot 0 = point 0

  for (int s = 0; s < NM - 1; ++s) {  // compute winners for slots 1..1023
    float bd = -1.0f, bx = 0.0f, by = 0.0f, bz = 0.0f;
#pragma unroll
    for (int j = 0; j < 16; ++j) {
      // match numpy: plain mul, left-assoc adds, no contraction
      float dx = __fsub_rn(px[j], sx);
      float dy = __fsub_rn(py[j], sy);
      float dz = __fsub_rn(pz[j], sz);
      float d2 = __fadd_rn(__fadd_rn(__fmul_rn(dx, dx), __fmul_rn(dy, dy)), __fmul_rn(dz, dz));
      float nd = fminf(dist[j], d2);
      dist[j] = nd;
      bool g = nd > bd;  // strict > keeps lowest j (= lowest index)
      bd = g ? nd : bd;
      bx = g ? px[j] : bx;
      by = g ? py[j] : by;
      bz = g ? pz[j] : bz;
    }
    // wave argmax: DPP value max, lowest tied lane (= lowest index) writes cand
    float wmax = wave_fmax(bd);
    u64 m = __ballot(bd == wmax);
    if (lane == __ffsll((long long)m) - 1) red[s & 1][wid] = make_float4(bd, bx, by, bz);
    __syncthreads();
    // 4-way serial argmax, ascending wid + strict > == global first-max
    float4 c0 = red[s & 1][0], c1 = red[s & 1][1], c2 = red[s & 1][2], c3 = red[s & 1][3];
    float bdd = c0.x; sx = c0.y; sy = c0.z; sz = c0.w;
    bool g1 = c1.x > bdd; bdd = g1 ? c1.x : bdd; sx = g1 ? c1.y : sx; sy = g1 ? c1.z : sy; sz = g1 ? c1.w : sz;
    bool g2 = c2.x > bdd; bdd = g2 ? c2.x : bdd; sx = g2 ? c2.y : sx; sy = g2 ? c2.z : sy; sz = g2 ? c2.w : sz;
    bool g3 = c3.x > bdd; bdd = g3 ? c3.x : bdd; sx = g3 ? c3.y : sx; sy = g3 ? c3.z : sy; sz = g3 ? c3.w : sz;
    // capture slot s+1 into the shift queue (static indices only)
    if (tid == ((s + 1) & 255)) {
      w3x = w2x; w3y = w2y; w3z = w2z;
      w2x = w1x; w2y = w1y; w2z = w1z;
      w1x = w0x; w1y = w0y; w1z = w0z;
      w0x = sx;  w0y = sy;  w0z = sz;
    }
  }
  // thread t holds slots t(w3), t+256(w2), t+512(w1), t+768(w0); coalesced write
  float* Ox = out_setloc + (b * 3 + 0) * NM;
  float* Oy = out_setloc + (b * 3 + 1) * NM;
  float* Oz = out_setloc + (b * 3 + 2) * NM;
  Ox[tid] = w3x;       Oy[tid] = w3y;       Oz[tid] = w3z;
  Ox[tid + 256] = w2x; Oy[tid + 256] = w2y; Oz[tid + 256] = w2z;
  Ox[tid + 512] = w1x; Oy[tid + 512] = w1y; Oz[tid + 512] = w1z;
  Ox[tid + 768] = w0x; Oy[tid + 768] = w0y; Oz[tid + 768] = w0z;
}

// ---------- kernel 3: kNN (one wave per query, DPP-min extraction) ----------

__global__ __launch_bounds__(256) void knn_kernel(const float* __restrict__ loc,
                                                  const float* __restrict__ setloc,
                                                  int* __restrict__ ws_knn) {
  const int wq = blockIdx.x * 4 + (threadIdx.x >> 6);  // query id, < NB*NM
  const int lane = threadIdx.x & 63;
  const int b = wq >> 10, mq = wq & 1023;
  const float* Sb = setloc + (size_t)b * 3 * NM;
  float xs = Sb[mq], ys = Sb[NM + mq], zs = Sb[2 * NM + mq];
  float sqs = __fadd_rn(__fadd_rn(__fmul_rn(xs, xs), __fmul_rn(ys, ys)), __fmul_rn(zs, zs));
  const float* Lx = loc + (size_t)b * 3 * NN;
  const float* Ly = Lx + NN;
  const float* Lz = Ly + NN;
  const float INF = __int_as_float(0x7f800000);

  // per-lane two smallest (value, index); lane owns points p = j*64+lane
  float k1 = INF, k2 = INF;
  unsigned i1 = 0xFFFFFFFFu, i2 = 0xFFFFFFFFu;
#pragma unroll 8
  for (int j = 0; j < 64; ++j) {
    int p = j * 64 + lane;
    float x = Lx[p], y = Ly[p], z = Lz[p];
    float sql = __fadd_rn(__fadd_rn(__fmul_rn(x, x), __fmul_rn(y, y)), __fmul_rn(z, z));
    float cr  = __fadd_rn(__fadd_rn(__fmul_rn(xs, x), __fmul_rn(ys, y)), __fmul_rn(zs, z));
    float d2  = __fsub_rn(__fadd_rn(sqs, sql), __fmul_rn(2.0f, cr));
    if (d2 < k1)      { k2 = k1; i2 = i1; k1 = d2; i1 = (unsigned)p; }
    else if (d2 < k2) { k2 = d2; i2 = (unsigned)p; }
  }

  u64 used = 0;        // per-lane mask of extracted j-slots
  unsigned keep = 0;   // lane s holds round-s winner
  for (int s = 0; s < NK; ++s) {
    float wmin = wave_fmin(k1);
    u64 mask = __ballot(k1 == wmin);
    int ownerLane;
    if (__popcll(mask) > 1) {
      // exact tie-break: smallest global index among tied lanes
      unsigned cand = (k1 == wmin) ? i1 : 0xFFFFFFFFu;
      unsigned minp = wave_umin(cand);
      u64 m2 = __ballot(k1 == wmin && i1 == minp);
      ownerLane = __ffsll((long long)m2) - 1;
    } else {
      ownerLane = __ffsll((long long)mask) - 1;
    }
    unsigned widx = (unsigned)__builtin_amdgcn_readlane((int)i1, ownerLane);
    if (lane == s) keep = widx;
    if (lane == ownerLane) {
      used |= 1ull << (i1 >> 6);
      k1 = k2; i1 = i2;
      k2 = INF; i2 = 0xFFFFFFFFu;
      if (__float_as_uint(k1) == 0x7f800000u) {
        // rare refill: recompute this lane's remaining distances (L2-hot loc)
#pragma unroll 8
        for (int j = 0; j < 64; ++j) {
          if (!((used >> j) & 1ull)) {
            int p = j * 64 + lane;
            float x = Lx[p], y = Ly[p], z = Lz[p];
            float sql = __fadd_rn(__fadd_rn(__fmul_rn(x, x), __fmul_rn(y, y)), __fmul_rn(z, z));
            float cr  = __fadd_rn(__fadd_rn(__fmul_rn(xs, x), __fmul_rn(ys, y)), __fmul_rn(zs, z));
            float d2  = __fsub_rn(__fadd_rn(sqs, sql), __fmul_rn(2.0f, cr));
            if (d2 < k1)      { k2 = k1; i2 = i1; k1 = d2; i1 = (unsigned)p; }
            else if (d2 < k2) { k2 = d2; i2 = (unsigned)p; }
          }
        }
      }
    }
  }
  if (lane < NK) ws_knn[(size_t)wq * NK + lane] = (int)keep;
}

// ---------- kernel 4: fused gather + 3-layer MLP + maxpool ----------

#define RELU8() { a0=fmaxf(a0,0.f); a1=fmaxf(a1,0.f); a2=fmaxf(a2,0.f); a3=fmaxf(a3,0.f); \
                  a4=fmaxf(a4,0.f); a5=fmaxf(a5,0.f); a6=fmaxf(a6,0.f); a7=fmaxf(a7,0.f); }
#define SCROW(Y, base) { Y[base]=a0; Y[base+1]=a1; Y[base+2]=a2; Y[base+3]=a3; \
                         Y[base+4]=a4; Y[base+5]=a5; Y[base+6]=a6; Y[base+7]=a7; }
#define SCAT8(Y) switch (ob) { \
    case 0: SCROW(Y, 0) break;  case 1: SCROW(Y, 8) break; \
    case 2: SCROW(Y, 16) break; case 3: SCROW(Y, 24) break; \
    case 4: SCROW(Y, 32) break; case 5: SCROW(Y, 40) break; \
    case 6: SCROW(Y, 48) break; case 7: SCROW(Y, 56) break; }
#define BFLY(a) { a = fmaxf(a, __shfl_xor(a, 16, 64)); a = fmaxf(a, __shfl_xor(a, 8, 64)); \
                  a = fmaxf(a, __shfl_xor(a, 4, 64));  a = fmaxf(a, __shfl_xor(a, 2, 64)); \
                  a = fmaxf(a, __shfl_xor(a, 1, 64)); }

// one 4-c chunk of row R accumulated into ACC (explicit float4 weight load)
#define ROW4(ACC, R, STRIDE) { \
    float4 w = *(const float4*)(wr + (R) * (STRIDE) + 4 * ch); \
    ACC = fmaf(w.x, x0, ACC); ACC = fmaf(w.y, x1, ACC); \
    ACC = fmaf(w.z, x2, ACC); ACC = fmaf(w.w, x3, ACC); }

#define CHUNK8(XS, STRIDE) { \
    float x0 = XS[4 * ch], x1 = XS[4 * ch + 1], x2 = XS[4 * ch + 2], x3 = XS[4 * ch + 3]; \
    ROW4(a0, 0, STRIDE) ROW4(a1, 1, STRIDE) ROW4(a2, 2, STRIDE) ROW4(a3, 3, STRIDE) \
    ROW4(a4, 4, STRIDE) ROW4(a5, 5, STRIDE) ROW4(a6, 6, STRIDE) ROW4(a7, 7, STRIDE) }

__global__ __launch_bounds__(256) void mlp_kernel(
    const float* __restrict__ featT, const float* __restrict__ loc,
    const float* __restrict__ setloc, const int* __restrict__ ws_knn,
    const float* __restrict__ W1p, const float* __restrict__ b1,
    const float* __restrict__ W2, const float* __restrict__ b2,
    const float* __restrict__ W3, const float* __restrict__ b3,
    float* __restrict__ out) {
  const int lane = threadIdx.x & 63;
  const int wix = blockIdx.x * 4 + (threadIdx.x >> 6);  // wave id, < 8192
  const int q = wix * 2 + (lane >> 5);                  // query id, < 16384
  const int col = lane & 31;                            // neighbor slot (k)
  const int b = q >> 10, mq = q & 1023;
  const int nk = ws_knn[(size_t)q * NK + col];

  // gather input column: 64 feat channels + 3 rel-loc + zero pad
  const float* fx = featT + ((size_t)(b * NN + nk)) * 64;
  float x[68];
#pragma unroll
  for (int i = 0; i < 16; ++i) {
    float4 v = *(const float4*)(fx + 4 * i);
    x[4 * i] = v.x; x[4 * i + 1] = v.y; x[4 * i + 2] = v.z; x[4 * i + 3] = v.w;
  }
  {
    const float* Lb = loc + (size_t)b * 3 * NN;
    const float* Sb = setloc + (size_t)b * 3 * NM;
    x[64] = Lb[nk] - Sb[mq];
    x[65] = Lb[NN + nk] - Sb[NM + mq];
    x[66] = Lb[2 * NN + nk] - Sb[2 * NM + mq];
    x[67] = 0.0f;  // pairs with W1p zero column
  }

  // layer 1: 68 -> 64 (padded)
  float y1[64];
#pragma unroll 1
  for (int ob = 0; ob < 8; ++ob) {
    const float* wr = W1p + (size_t)ob * 8 * 68;
    const float* bb = b1 + ob * 8;
    float a0 = bb[0], a1 = bb[1], a2 = bb[2], a3 = bb[3];
    float a4 = bb[4], a5 = bb[5], a6 = bb[6], a7 = bb[7];
#pragma unroll
    for (int ch = 0; ch < 17; ++ch) CHUNK8(x, 68)
    RELU8();
    SCAT8(y1);
  }

  // layer 2: 64 -> 64
  float y2[64];
#pragma unroll 1
  for (int ob = 0; ob < 8; ++ob) {
    const float* wr = W2 + (size_t)ob * 8 * 64;
    const float* bb = b2 + ob * 8;
    float a0 = bb[0], a1 = bb[1], a2 = bb[2], a3 = bb[3];
    float a4 = bb[4], a5 = bb[5], a6 = bb[6], a7 = bb[7];
#pragma unroll
    for (int ch = 0; ch < 16; ++ch) CHUNK8(y1, 64)
    RELU8();
    SCAT8(y2);
  }

  // layer 3: 64 -> 128, fused maxpool over the 32 columns + store
#pragma unroll 1
  for (int ob = 0; ob < 16; ++ob) {
    const float* wr = W3 + (size_t)ob * 8 * 64;
    const float* bb = b3 + ob * 8;
    float a0 = bb[0], a1 = bb[1], a2 = bb[2], a3 = bb[3];
    float a4 = bb[4], a5 = bb[5], a6 = bb[6], a7 = bb[7];
#pragma unroll
    for (int ch = 0; ch < 16; ++ch) CHUNK8(y2, 64)
    RELU8();
    BFLY(a0); BFLY(a1); BFLY(a2); BFLY(a3);
    BFLY(a4); BFLY(a5); BFLY(a6); BFLY(a7);
    if (col == 0) {
      float* op = out + ((size_t)b * 128 + ob * 8) * NM + mq;
      op[0] = a0;       op[NM] = a1;     op[2 * NM] = a2; op[3 * NM] = a3;
      op[4 * NM] = a4;  op[5 * NM] = a5; op[6 * NM] = a6; op[7 * NM] = a7;
    }
  }
}

// ---------- launch ----------

extern "C" void kernel_launch(void* const* d_in, const int* in_sizes, int n_in,
                              void* d_out, int out_size, void* d_ws, size_t ws_size,
                              hipStream_t stream) {
  (void)in_sizes; (void)n_in; (void)out_size; (void)ws_size;
  const float* feat = (const float*)d_in[0];
  const float* loc  = (const float*)d_in[1];
  const float* W1   = (const float*)d_in[2];
  const float* b1   = (const float*)d_in[3];
  const float* W2   = (const float*)d_in[4];
  const float* b2   = (const float*)d_in[5];
  const float* W3   = (const float*)d_in[6];
  const float* b3   = (const float*)d_in[7];
  float* out = (float*)d_out;

  char* ws = (char*)d_ws;
  int*   ws_knn   = (int*)ws;                           // 16*1024*32 i32 = 2 MB
  float* ws_featT = (float*)(ws + 2097152);             // 16*4096*64 f32 = 16.75 MB
  float* ws_w1p   = (float*)(ws + 2097152 + 16777216);  // 64*68 f32

  float* out_setfeat = out;                          // (16,128,1024)
  float* out_setloc  = out + (size_t)NB * 128 * NM;  // (16,3,1024)

  pad_w1<<<dim3(17), dim3(256), 0, stream>>>(W1, ws_w1p);
  transpose_feat<<<dim3((NB * NN * NC) / 256), dim3(256), 0, stream>>>(feat, ws_featT);
  fps_kernel<<<dim3(NB), dim3(256), 0, stream>>>(loc, out_setloc);
  knn_kernel<<<dim3((NB * NM) / 4), dim3(256), 0, stream>>>(loc, out_setloc, ws_knn);
  mlp_kernel<<<dim3((NB * NM) / 8), dim3(256), 0, stream>>>(
      ws_featT, loc, out_setloc, ws_knn, ws_w1p, b1, W2, b2, W3, b3, out_setfeat);
}